// Round 1
// 758.612 us; speedup vs baseline: 1.3468x; 1.3468x over previous
//
// HierarchicalPattern — rev8. R7 post-mortem: mask kernel = 726 of 1022 µs with
// MfmaUtil 0, HBM 14%, VALUBusy 40% -> latency/LDS-pipe bound. Cost center:
// phase 2 ran 4q x 32 serial extract-max iterations per block, each a 6-level
// u64 __shfl_xor butterfly (ds_bpermute = LDS pipe!) + 2 barriers + LDS
// round-trip: ~36M LDS-pipe ops, ~1M barriers grid-wide. rev8 replaces it with
// a ballot-count binary threshold search: top-32 == {u > m32} + first
// (32-count) ties at m32 in ascending k. 32 fixed bisection trials, all 4
// queries per trial; per-wave counts packed 4x u16 in ONE u64 -> 1 ds_write +
// 2 broadcast ds_read + 1 barrier per trial (double-buffered red). v_cmp
// ballots + s_bcnt1 replace the bpermute storm. Exact ties: T==need fast path;
// T>need (float collision, ~never) resolved c-major by thread 0. Output:
// selection marks an LDS bitmap; fill writes each uint4 exactly once -> kills
// the scatter RMW (WRITE_SIZE 622 MB -> ~134 MB ideal). Feat kernel unchanged.
#include <hip/hip_runtime.h>
#include <hip/hip_fp16.h>
#include <cstdint>

#define SEQ 4096
#define NB 4
#define DMODEL 1024
#define ID 64
#define LW 16
#define GK 32
#define TQ 4

#define NEG_INF (-__builtin_inff())
#define MASKED4 0xFBFFFBFFu

__device__ __forceinline__ float2 h2f2(unsigned int u) {
    __half2 h = *reinterpret_cast<__half2*>(&u);
    return __half22float2(h);
}

// ---------------- Kernel 1: lf rows + gfT (fp16 in, f32 out) -----------------
// (unchanged from rev7 — will get its own round once mask is off the critical
// path; it runs ~295 µs vs a ~30 µs VALU/HBM floor.)
__global__ __launch_bounds__(256)
void hp_feat_v7(const unsigned short* __restrict__ x,
                const unsigned short* __restrict__ Wl,
                const unsigned short* __restrict__ Wg,
                float* __restrict__ lf, float* __restrict__ gfT)
{
    __shared__ float xs[32][68];     // [k][row]
    __shared__ float ws[32][68];     // [k][col]
    __shared__ float trans[64][68];  // gf transpose staging

    const int tid = threadIdx.x;
    const int half = blockIdx.x & 1;
    const long row0 = (long)(blockIdx.x >> 1) * 64;
    const unsigned short* W = half ? Wg : Wl;
    const int tx = tid & 15, ty = tid >> 4;

    float acc[4][4];
#pragma unroll
    for (int r = 0; r < 4; r++)
#pragma unroll
        for (int c = 0; c < 4; c++) acc[r][c] = 0.f;

    for (int k0 = 0; k0 < DMODEL; k0 += 32) {
        {   // x tile: 64 rows x 32 k; 8 fp16 per thread
            int r = tid >> 2, c8 = (tid & 3) * 8;
            uint4 v = *(const uint4*)(x + (row0 + r) * DMODEL + k0 + c8);
            float2 f;
            f = h2f2(v.x); xs[c8 + 0][r] = f.x; xs[c8 + 1][r] = f.y;
            f = h2f2(v.y); xs[c8 + 2][r] = f.x; xs[c8 + 3][r] = f.y;
            f = h2f2(v.z); xs[c8 + 4][r] = f.x; xs[c8 + 5][r] = f.y;
            f = h2f2(v.w); xs[c8 + 6][r] = f.x; xs[c8 + 7][r] = f.y;
        }
        {   // W tile: 64 cols x 32 k
            int r = tid >> 2, c8 = (tid & 3) * 8;
            uint4 v = *(const uint4*)(W + (long)r * DMODEL + k0 + c8);
            float2 f;
            f = h2f2(v.x); ws[c8 + 0][r] = f.x; ws[c8 + 1][r] = f.y;
            f = h2f2(v.y); ws[c8 + 2][r] = f.x; ws[c8 + 3][r] = f.y;
            f = h2f2(v.z); ws[c8 + 4][r] = f.x; ws[c8 + 5][r] = f.y;
            f = h2f2(v.w); ws[c8 + 6][r] = f.x; ws[c8 + 7][r] = f.y;
        }
        __syncthreads();
#pragma unroll
        for (int kk = 0; kk < 32; kk++) {
            float4 a  = *(const float4*)&xs[kk][ty * 4];
            float4 bv = *(const float4*)&ws[kk][tx * 4];
            const float ar[4] = {a.x, a.y, a.z, a.w};
            const float bc[4] = {bv.x, bv.y, bv.z, bv.w};
#pragma unroll
            for (int r = 0; r < 4; r++)
#pragma unroll
                for (int c = 0; c < 4; c++)
                    acc[r][c] = fmaf(ar[r], bc[c], acc[r][c]);
        }
        __syncthreads();
    }

    if (!half) {        // lf rows, row-major, coalesced float4
#pragma unroll
        for (int r = 0; r < 4; r++) {
            float4 st = make_float4(acc[r][0], acc[r][1], acc[r][2], acc[r][3]);
            *(float4*)(lf + (row0 + ty * 4 + r) * ID + tx * 4) = st;
        }
    } else {            // gfT[b][col][s]: LDS transpose then coalesced stores
#pragma unroll
        for (int r = 0; r < 4; r++)
#pragma unroll
            for (int c = 0; c < 4; c++)
                trans[tx * 4 + c][ty * 4 + r] = acc[r][c];
        __syncthreads();
        const int b = (int)(row0 >> 12), s0 = (int)(row0 & 4095);
        const int col = tid >> 2, rs = (tid & 3) * 16;
        float* dst = gfT + ((long)b * ID + col) * SEQ + s0 + rs;
#pragma unroll
        for (int u = 0; u < 4; u++)
            *(float4*)(dst + 4 * u) = *(const float4*)&trans[col][rs + 4 * u];
    }
}

// ---------------- Kernel 2: TQ=4 queries per block ---------------------------
// Phase 1 (unchanged): outer-product scores, thread t owns keys 1024c+4t+j.
// Phase 2 (NEW): biased-u32 scores; binary threshold search via ballots.
// Output (NEW): LDS bitmap -> single-pass fill, no scatter.
__global__ __launch_bounds__(256)
void hp_mask_v8(const float* __restrict__ lf, const float* __restrict__ gfT,
                unsigned short* __restrict__ out)
{
    __shared__ float qv[TQ][ID];
    __shared__ float lq[TQ][ID];
    __shared__ unsigned long long red[4][4];   // [slot][wave]; 4x u16 packed counts
    __shared__ unsigned int bitmap[TQ][SEQ / 32]; // 2 KiB selection bitmap
    __shared__ float lsc[TQ][LW];
    __shared__ unsigned short tm[256];         // rare tie path: per-thread masks

    const int tid = threadIdx.x;
    const int lane = tid & 63, w = tid >> 6;
    const int bq = blockIdx.x;            // b*(SEQ/TQ) + qgroup
    const int b = bq >> 10;
    const int q0 = (bq & 1023) * TQ;
    const float* gTb = gfT + (long)b * ID * SEQ;
    const float* lfb = lf + (long)b * SEQ * ID;

    {   // qv[qi][d] = gfT[b][d][q0+qi]; lq from lf rows; zero bitmap
        int d = tid >> 2, qi = tid & 3;
        qv[qi][d] = gTb[(long)d * SEQ + q0 + qi];
        int qi2 = tid >> 6, d2 = tid & 63;
        lq[qi2][d2] = lfb[(long)(q0 + qi2) * ID + d2];
        ((unsigned int*)bitmap)[tid] = 0u;
        ((unsigned int*)bitmap)[tid + 256] = 0u;
    }
    __syncthreads();

    // ---- Phase 1: register-resident scores (unchanged) ----------------------
    float acc[4][4][TQ];                  // [c][j][qi]
#pragma unroll
    for (int c = 0; c < 4; c++)
#pragma unroll
        for (int j = 0; j < 4; j++)
#pragma unroll
            for (int qi = 0; qi < TQ; qi++) acc[c][j][qi] = 0.f;

    for (int d = 0; d < ID; d++) {
        float qd[TQ];
#pragma unroll
        for (int qi = 0; qi < TQ; qi++) qd[qi] = qv[qi][d];  // uniform broadcast
        const float4* rowp = (const float4*)(gTb + (long)d * SEQ);
#pragma unroll
        for (int c = 0; c < 4; c++) {
            float4 kv = rowp[c * 256 + tid];
#pragma unroll
            for (int qi = 0; qi < TQ; qi++) {
                acc[c][0][qi] = fmaf(kv.x, qd[qi], acc[c][0][qi]);
                acc[c][1][qi] = fmaf(kv.y, qd[qi], acc[c][1][qi]);
                acc[c][2][qi] = fmaf(kv.z, qd[qi], acc[c][2][qi]);
                acc[c][3][qi] = fmaf(kv.w, qd[qi], acc[c][3][qi]);
            }
        }
    }

    // ---- Phase 2a: biased-u32 keys (banned -> 0; order == value desc) -------
    // u = bits(relu(s)) + 1 is monotone in s for s >= 0; banned stay below the
    // threshold since m32 >= 1 always (>= 4080 allowed keys per query).
    unsigned int uv[4][4][TQ];
#pragma unroll
    for (int c = 0; c < 4; c++)
#pragma unroll
        for (int j = 0; j < 4; j++) {
            const int k = 1024 * c + 4 * tid + j;
#pragma unroll
            for (int qi = 0; qi < TQ; qi++) {
                const int q = q0 + qi;
                const bool banned = (k <= q) && (k >= q - (LW - 1));
                uv[c][j][qi] = banned ? 0u
                    : (__float_as_uint(fmaxf(acc[c][j][qi], 0.f)) + 1u);
            }
        }

    // ---- Phase 2b: bisection for m32 = 32nd-largest u, all 4 queries --------
    // Invariant: count(u >= lo) >= GK, count(u >= hi) < GK. 32 trials close a
    // 2^32 range. One barrier per trial (double-buffered red).
    unsigned int lo[TQ], hi[TQ];
#pragma unroll
    for (int qi = 0; qi < TQ; qi++) { lo[qi] = 0u; hi[qi] = 0xFFFFFFFFu; }

#pragma unroll 1
    for (int it = 0; it < 32; ++it) {
        unsigned int mid[TQ];
        unsigned long long pc = 0ull;
#pragma unroll
        for (int qi = 0; qi < TQ; qi++) {
            mid[qi] = lo[qi] + ((hi[qi] - lo[qi]) >> 1);
            int cnt = 0;
#pragma unroll
            for (int c = 0; c < 4; c++)
#pragma unroll
                for (int j = 0; j < 4; j++)
                    cnt += __popcll(__ballot(uv[c][j][qi] >= mid[qi]));
            pc |= (unsigned long long)(unsigned int)cnt << (16 * qi);
        }
        if (lane == 0) red[it & 1][w] = pc;
        __syncthreads();
        const unsigned long long tot = red[it & 1][0] + red[it & 1][1]
                                     + red[it & 1][2] + red[it & 1][3];
#pragma unroll
        for (int qi = 0; qi < TQ; qi++) {
            const unsigned int cnt =
                (unsigned int)((tot >> (16 * qi)) & 0xFFFFull);
            if (cnt >= GK) lo[qi] = mid[qi]; else hi[qi] = mid[qi];
        }
    }

    // ---- Phase 2c: final counts: C1 = #{u > m32}, T = #{u == m32} -----------
    int C1[TQ], T[TQ], need[TQ];
    {
        unsigned long long pg = 0ull, pe = 0ull;
#pragma unroll
        for (int qi = 0; qi < TQ; qi++) {
            int cg = 0, ce = 0;
#pragma unroll
            for (int c = 0; c < 4; c++)
#pragma unroll
                for (int j = 0; j < 4; j++) {
                    const unsigned int v = uv[c][j][qi];
                    cg += __popcll(__ballot(v > lo[qi]));
                    ce += __popcll(__ballot(v == lo[qi]));
                }
            pg |= (unsigned long long)(unsigned int)cg << (16 * qi);
            pe |= (unsigned long long)(unsigned int)ce << (16 * qi);
        }
        if (lane == 0) { red[2][w] = pg; red[3][w] = pe; }
        __syncthreads();
        const unsigned long long tg = red[2][0] + red[2][1] + red[2][2] + red[2][3];
        const unsigned long long te = red[3][0] + red[3][1] + red[3][2] + red[3][3];
#pragma unroll
        for (int qi = 0; qi < TQ; qi++) {
            C1[qi]   = (int)((tg >> (16 * qi)) & 0xFFFFull);
            T[qi]    = (int)((te >> (16 * qi)) & 0xFFFFull);
            need[qi] = GK - C1[qi];           // >= 1; T >= need guaranteed
        }
    }

    // ---- Phase 2d: mark selections in bitmap --------------------------------
#pragma unroll
    for (int qi = 0; qi < TQ; qi++) {
        const bool allties = (T[qi] == need[qi]);
#pragma unroll
        for (int c = 0; c < 4; c++)
#pragma unroll
            for (int j = 0; j < 4; j++) {
                const unsigned int v = uv[c][j][qi];
                const bool sel_ = (v > lo[qi]) | (allties & (v == lo[qi]));
                if (sel_) {
                    const int k = 1024 * c + 4 * tid + j;
                    atomicOr(&bitmap[qi][k >> 5], 1u << (k & 31));
                }
            }
    }

    // Rare exact-tie path (float collisions at the boundary): pick the `need`
    // smallest-k ties in ascending (c, tid, j) == ascending k. Block-uniform
    // trigger -> barriers inside are safe.
#pragma unroll 1
    for (int qi = 0; qi < TQ; qi++) {
        if (T[qi] > need[qi]) {
            unsigned int m16 = 0u;
#pragma unroll
            for (int c = 0; c < 4; c++)
#pragma unroll
                for (int j = 0; j < 4; j++)
                    if (uv[c][j][qi] == lo[qi]) m16 |= 1u << (c * 4 + j);
            tm[tid] = (unsigned short)m16;
            __syncthreads();
            if (tid == 0) {
                int taken = 0;
                for (int c = 0; c < 4 && taken < need[qi]; c++)
                    for (int t = 0; t < 256 && taken < need[qi]; t++) {
                        const unsigned int nib = ((unsigned int)tm[t] >> (c * 4)) & 15u;
                        for (int j = 0; j < 4 && taken < need[qi]; j++)
                            if ((nib >> j) & 1u) {
                                const int k = 1024 * c + 4 * t + j;
                                atomicOr(&bitmap[qi][k >> 5], 1u << (k & 31));
                                taken++;
                            }
                    }
            }
            __syncthreads();
        }
    }

    // ---- local window: 16 scores per query, stable top-ks -> bitmap ---------
    if (tid < TQ * LW) {
        int qi = tid >> 4, wnd = tid & 15;
        int q = q0 + qi;
        int win = q - (LW - 1) + wnd;
        float v = NEG_INF;
        if (win >= 0) {
            const float4* kr = (const float4*)(lfb + (long)win * ID);
            float s = 0.f;
#pragma unroll
            for (int d = 0; d < 16; d++) {
                float4 kvv = kr[d];
                const float4 qd = *(const float4*)&lq[qi][d * 4];
                s = fmaf(kvv.x, qd.x, s); s = fmaf(kvv.y, qd.y, s);
                s = fmaf(kvv.z, qd.z, s); s = fmaf(kvv.w, qd.w, s);
            }
            v = fmaxf(s, 0.f);
        }
        lsc[qi][wnd] = v;
    }
    __syncthreads();
    if (tid < TQ) {
        int qi = tid, q = q0 + qi;
        int L = (q + 1 < LW) ? q + 1 : LW;
        int ks = L / 5; if (ks < 1) ks = 1;   // == max(1, int(L*0.2))
        for (int t = 0; t < ks; t++) {
            float best = NEG_INF; int bi = 0;
            for (int wnd = 0; wnd < LW; wnd++) {
                float v = lsc[qi][wnd];
                if (v > best) { best = v; bi = wnd; }  // strict > keeps lowest idx
            }
            lsc[qi][bi] = NEG_INF;
            const int win = q - (LW - 1) + bi;
            atomicOr(&bitmap[qi][win >> 5], 1u << (win & 31));
        }
    }
    __syncthreads();

    // ---- output: single-pass fill from bitmap (each line written once) ------
    uint4* orow = (uint4*)(out + ((long)b * SEQ + q0) * SEQ);
#pragma unroll
    for (int i = 0; i < TQ * SEQ / 8 / 256; i++) {  // 8 iters, 2048 uint4
        const int li = i * 256 + tid;
        const int qi = li >> 9;          // 512 uint4 per row
        const int w8 = li & 511;         // cols 8*w8 .. 8*w8+7
        const unsigned int bits =
            (bitmap[qi][w8 >> 2] >> ((w8 & 3) * 8)) & 0xFFu;
        uint4 v;
        v.x = MASKED4 & ~(((bits &   1u) ? 0x0000FFFFu : 0u) |
                          ((bits &   2u) ? 0xFFFF0000u : 0u));
        v.y = MASKED4 & ~(((bits &   4u) ? 0x0000FFFFu : 0u) |
                          ((bits &   8u) ? 0xFFFF0000u : 0u));
        v.z = MASKED4 & ~(((bits &  16u) ? 0x0000FFFFu : 0u) |
                          ((bits &  32u) ? 0xFFFF0000u : 0u));
        v.w = MASKED4 & ~(((bits &  64u) ? 0x0000FFFFu : 0u) |
                          ((bits & 128u) ? 0xFFFF0000u : 0u));
        orow[li] = v;
    }
}

extern "C" void kernel_launch(void* const* d_in, const int* in_sizes, int n_in,
                              void* d_out, int out_size, void* d_ws, size_t ws_size,
                              hipStream_t stream) {
    const unsigned short* x  = (const unsigned short*)d_in[0];
    const unsigned short* Wl = (const unsigned short*)d_in[1];
    // d_in[2] = W_medium: dead in the reference — skipped.
    const unsigned short* Wg = (const unsigned short*)d_in[3];
    unsigned short* out = (unsigned short*)d_out;

    float* lf  = (float*)d_ws;                        // 4 MiB, row-major
    float* gfT = lf + (long)NB * SEQ * ID;            // 4 MiB, [b][d][k]

    hp_feat_v7<<<(NB * SEQ / 64) * 2, 256, 0, stream>>>(x, Wl, Wg, lf, gfT);
    hp_mask_v8<<<NB * SEQ / TQ, 256, 0, stream>>>(lf, gfT, out);
}